// Round 10
// baseline (4388.544 us; speedup 1.0000x reference)
//
#include <hip/hip_runtime.h>
#include <hip/hip_bf16.h>

// KWSNet: conv1d+relu -> 2x GRU (fwd-scan, two weight sets) -> sliding mean -> linear(2)
// B=64, M=80, T=2000, C=H=256, K=5; Tc=1996, W=96, Tout=1901, out (1901,1,64,2) fp32.
//
// Chunked pipeline (8 x <=250 steps): conv -> proj (fp16 MFMA) -> persistent GRU scan.
//
// Scan design (R10): the compiler's register budget is a hard 65536/B unified
// slots per block (2 blocks/CU target; R3-R9: immune to launch_bounds /
// waves_per_eu / LDS occupancy). fp16 W_hh needs 98304 slots -> can never be
// fully register-resident. Split store instead, B=256 (grants 256 regs/thread):
//   cols [0,128)  : fp16 in 192 VGPRs/thread (proven R3 pattern, no spill)
//   cols [128,256): int8 in LDS (96 KB), v_dot4_i32_i8 against int8-quantized h
// One thread per hidden unit -> one barrier/step; xg prefetched a step ahead.

#define TT    2000
#define TC    1996
#define NB    64
#define MCH   80
#define NH    256
#define NN    1536           // 2 * 3H
#define TOUT  1901
#define TCH   250            // chunk length (last chunk = 246)
#define NCHK  8
#define CROWS (TCH * NB)     // 16000 rows per chunk

typedef _Float16 h2_t __attribute__((ext_vector_type(2)));
typedef _Float16 h8_t __attribute__((ext_vector_type(8)));
typedef float    f4_t __attribute__((ext_vector_type(4)));

#define WQSCALE 254.0f
#define INV8    (1.0f / (254.0f * 127.0f))

// ---------------- workspace layout (bytes), total ~59.9 MB ----------------
#define OFF_SEQC ((size_t)0)            // fp16 [CROWS][256]     = 8,192,000
#define OFF_XG   ((size_t)8192000)      // fp16 [2][CROWS][768]  = 49,152,000
#define OFF_WT   ((size_t)57344000)     // fp32 [400][256]       = 409,600
#define OFF_WCAT ((size_t)57753600)     // fp16 [1536][256]      = 786,432
#define OFF_PSUM ((size_t)58540032)     // fp32 [TC][64][2]      = 1,021,952
#define OFF_HST  ((size_t)59561984)     // fp32 [128][256]       = 131,072
#define OFF_WQ8  ((size_t)59693056)     // u32  [2][3][8][256][4]= 196,608  (int8-packed W_hh cols 128..255)

// ---------------- prep: transpose conv_w, fp16 w_ih concat, zero psum, quantize W_hh tail ----------------
__global__ void prep_kernel(const float* __restrict__ conv_w,
                            const float* __restrict__ wihf,
                            const float* __restrict__ wihr,
                            const float* __restrict__ whhf,
                            const float* __restrict__ whhr,
                            float* __restrict__ wT,
                            _Float16* __restrict__ wcat,
                            float* __restrict__ psum,
                            unsigned* __restrict__ wq8) {
    int idx = blockIdx.x * 256 + threadIdx.x;
    if (idx < 400 * 256) {
        int c = idx & 255, mk = idx >> 8;
        wT[idx] = conv_w[c * 400 + mk];
    }
    int i2 = idx - 400 * 256;
    if (i2 >= 0 && i2 < NN * 256) {
        int k = i2 & 255, n = i2 >> 8;
        float v = (n < 768) ? wihf[n * 256 + k] : wihr[(n - 768) * 256 + k];
        wcat[i2] = (_Float16)v;
    }
    int i3 = idx - (400 * 256 + NN * 256);
    if (i3 >= 0 && i3 < TC * 64 * 2) psum[i3] = 0.f;
    int i4 = idx - (400 * 256 + NN * 256 + TC * 64 * 2);
    if (i4 >= 0 && i4 < 2 * 3 * 32 * 256) {
        // e = ((d*3+g)*32 + j)*256 + r ; uint packs cols 128+4j..+3 of row g*256+r
        int r  = i4 & 255;
        int j  = (i4 >> 8) & 31;
        int dg = i4 >> 13;
        int d  = dg / 3, g = dg - d * 3;
        const float* whh = d ? whhr : whhf;
        const float* wp = whh + (size_t)(g * 256 + r) * 256 + 128 + 4 * j;
        unsigned v = 0;
#pragma unroll
        for (int kk = 0; kk < 4; ++kk) {
            float q = rintf(wp[kk] * WQSCALE);
            q = fminf(fmaxf(q, -127.f), 127.f);
            v |= ((unsigned)((int)q & 0xFF)) << (8 * kk);
        }
        // store in scan-read order: uint index = d*24576 + (g*8 + j/4)*1024 + r*4 + (j%4)
        wq8[(size_t)d * 24576 + (size_t)(g * 8 + (j >> 2)) * 1024 + r * 4 + (j & 3)] = v;
    }
}

// ---------------- conv1d(valid,K=5)+bias+relu -> seqc fp16 [t_local*64+b][c] ----------------
__global__ __launch_bounds__(256, 2)
void conv_kernel(const float* __restrict__ x, const float* __restrict__ wT,
                 const float* __restrict__ conv_b, _Float16* __restrict__ seqc,
                 int t_base, int t_len) {
    __shared__ float xs[MCH][68];
    int tile = blockIdx.x;           // 0..3
    int b    = blockIdx.y;           // 0..63
    int tid  = threadIdx.x;
    for (int idx = tid; idx < MCH * 68; idx += 256) {
        int m = idx / 68, i = idx - m * 68;
        int tt = t_base + tile * 64 + i;
        xs[m][i] = (tt < TT) ? x[(size_t)b * (MCH * TT) + m * TT + tt] : 0.f;
    }
    __syncthreads();
    int lane = tid & 63, tg = tid >> 6;   // wave tg: t-range [tg*16, tg*16+16)
    float acc[4][16];
#pragma unroll
    for (int cq = 0; cq < 4; ++cq)
#pragma unroll
        for (int t = 0; t < 16; ++t) acc[cq][t] = 0.f;

    for (int m = 0; m < MCH; ++m) {
        float xr_[20];
#pragma unroll
        for (int q = 0; q < 5; ++q) {
            float4 v = *(const float4*)&xs[m][tg * 16 + q * 4];
            xr_[q * 4 + 0] = v.x; xr_[q * 4 + 1] = v.y;
            xr_[q * 4 + 2] = v.z; xr_[q * 4 + 3] = v.w;
        }
#pragma unroll
        for (int cq = 0; cq < 4; ++cq) {
            int c = lane + cq * 64;
            const float* wp = wT + (size_t)(m * 5) * 256 + c;
            float w0_ = wp[0], w1_ = wp[256], w2_ = wp[512], w3_ = wp[768], w4_ = wp[1024];
#pragma unroll
            for (int t = 0; t < 16; ++t)
                acc[cq][t] += w0_ * xr_[t] + w1_ * xr_[t + 1] + w2_ * xr_[t + 2]
                            + w3_ * xr_[t + 3] + w4_ * xr_[t + 4];
        }
    }
#pragma unroll
    for (int cq = 0; cq < 4; ++cq) {
        int c = lane + cq * 64;
        float cb = conv_b[c];
        for (int t = 0; t < 16; ++t) {
            int tl = tile * 64 + tg * 16 + t;     // t within chunk
            if (tl < t_len) {
                float v = acc[cq][t] + cb;
                v = v > 0.f ? v : 0.f;
                seqc[((size_t)tl * 64 + b) * 256 + c] = (_Float16)v;
            }
        }
    }
}

// ---------------- proj: xg[d][row][j] = seqc @ w_ih^T + b_ih (fp16 MFMA 16x16x32) ----------------
__global__ __launch_bounds__(256, 2)
void proj_kernel(const _Float16* __restrict__ seqc, const _Float16* __restrict__ wcat,
                 const float* __restrict__ bihf, const float* __restrict__ bihr,
                 _Float16* __restrict__ xg) {
    __shared__ __align__(16) _Float16 As[128][72];
    __shared__ __align__(16) _Float16 Bs[128][72];
    int row0 = blockIdx.x * 128;     // up to 125 tiles
    int n0   = blockIdx.y * 128;     // 12 tiles
    int tid  = threadIdx.x;
    int lane = tid & 63, wv = tid >> 6;
    int wr = wv >> 1, wc = wv & 1;                 // 2x2 waves of 64x64
    int fm = lane & 15, fq = lane >> 4;            // fragment index, quad
    f4_t acc[4][4];
#pragma unroll
    for (int mt = 0; mt < 4; ++mt)
#pragma unroll
        for (int nt = 0; nt < 4; ++nt) acc[mt][nt] = (f4_t){0.f, 0.f, 0.f, 0.f};

    int r = tid >> 1, part = tid & 1;
    for (int kc = 0; kc < 4; ++kc) {
        const uint4* srcA = (const uint4*)&seqc[(size_t)(row0 + r) * 256 + kc * 64 + part * 32];
        const uint4* srcB = (const uint4*)&wcat[(size_t)(n0 + r) * 256 + kc * 64 + part * 32];
        uint4* dstA = (uint4*)&As[r][part * 32];
        uint4* dstB = (uint4*)&Bs[r][part * 32];
        dstA[0] = srcA[0]; dstA[1] = srcA[1]; dstA[2] = srcA[2]; dstA[3] = srcA[3];
        dstB[0] = srcB[0]; dstB[1] = srcB[1]; dstB[2] = srcB[2]; dstB[3] = srcB[3];
        __syncthreads();
#pragma unroll
        for (int ks = 0; ks < 64; ks += 32) {
            h8_t af[4], bf[4];
#pragma unroll
            for (int mt = 0; mt < 4; ++mt)
                af[mt] = *(const h8_t*)&As[wr * 64 + mt * 16 + fm][ks + fq * 8];
#pragma unroll
            for (int nt = 0; nt < 4; ++nt)
                bf[nt] = *(const h8_t*)&Bs[wc * 64 + nt * 16 + fm][ks + fq * 8];
#pragma unroll
            for (int mt = 0; mt < 4; ++mt)
#pragma unroll
                for (int nt = 0; nt < 4; ++nt)
                    acc[mt][nt] = __builtin_amdgcn_mfma_f32_16x16x32_f16(
                        af[mt], bf[nt], acc[mt][nt], 0, 0, 0);
        }
        __syncthreads();
    }
    // epilogue: C col = lane&15 (n-dim), row = (lane>>4)*4 + reg (m-dim)
#pragma unroll
    for (int nt = 0; nt < 4; ++nt) {
        int col = n0 + wc * 64 + nt * 16 + fm;
        int d = (col < 768) ? 0 : 1;
        int j = col - d * 768;
        float bias = d ? bihr[j] : bihf[j];
        size_t obase = (size_t)d * CROWS * 768 + j;
#pragma unroll
        for (int mt = 0; mt < 4; ++mt) {
            int row = row0 + wr * 64 + mt * 16 + fq * 4;
#pragma unroll
            for (int rr = 0; rr < 4; ++rr)
                xg[obase + (size_t)(row + rr) * 768] = (_Float16)(acc[mt][nt][rr] + bias);
        }
    }
}

// ---------------- persistent GRU scan chunk: 1 block (256 thr) per (direction, batch) ----------------
#define BC2(u) __builtin_bit_cast(h2_t, (u))
#define SD4(a, b, c) __builtin_amdgcn_sdot4((int)(a), (int)(b), (c), false)

__global__ __launch_bounds__(256)
void scan_kernel(const _Float16* __restrict__ xg,
                 const float* __restrict__ whhf, const float* __restrict__ whhr,
                 const float* __restrict__ bhhf, const float* __restrict__ bhhr,
                 const float* __restrict__ clf_w, const uint4* __restrict__ wq8,
                 float* __restrict__ psum, float* __restrict__ hstate,
                 int t0, int len, int first) {
    int blk = blockIdx.x;
    int d = blk >> 6, b = blk & 63;
    int i = threadIdx.x;
    const float* whh = d ? whhr : whhf;
    const float* bhh = d ? bhhr : bhhf;

    __shared__ __align__(16) _Float16 hbuf[2][256];
    __shared__ __align__(16) unsigned hq8[2][32];
    __shared__ __align__(16) uint4 lw8q[3][8][256];   // 96 KB int8 weights, cols 128..255

    // stage int8 weights: 6144 uint4, 24 per thread (coalesced, conflict-free)
    {
        const uint4* src = wq8 + (size_t)d * 6144;
        uint4* dst = &lw8q[0][0][0];
#pragma unroll
        for (int k = 0; k < 24; ++k) dst[k * 256 + i] = src[k * 256 + i];
    }

    // fp16 register weights: rows {i,i+256,i+512}, cols [0,128) -> 3 x 64 h2 = 192 VGPRs
    h2_t w0[64], w1[64], w2[64];
    {
        const float* p0 = whh + (size_t)i * 256;
        const float* p1 = whh + (size_t)(i + 256) * 256;
        const float* p2 = whh + (size_t)(i + 512) * 256;
#pragma unroll
        for (int c = 0; c < 64; ++c) {
            float2 f0 = *(const float2*)(p0 + 2 * c);
            float2 f1 = *(const float2*)(p1 + 2 * c);
            float2 f2 = *(const float2*)(p2 + 2 * c);
            w0[c] = (h2_t){(_Float16)f0.x, (_Float16)f0.y};
            w1[c] = (h2_t){(_Float16)f1.x, (_Float16)f1.y};
            w2[c] = (h2_t){(_Float16)f2.x, (_Float16)f2.y};
        }
    }
    float bhr = bhh[i], bhz = bhh[256 + i], bhn = bhh[512 + i];
    float cw0 = clf_w[d * 256 + i];          // clf_w[0][d*256+i]
    float cw1 = clf_w[512 + d * 256 + i];    // clf_w[1][d*256+i]
    float h = first ? 0.f : hstate[(size_t)blk * 256 + i];

    hbuf[0][i] = (_Float16)h;
    if (i >= 128)
        ((char*)&hq8[0][0])[i - 128] = (char)(int)rintf(h * 127.f);
    __syncthreads();

    const _Float16* xgp = xg + (size_t)d * CROWS * 768 + (size_t)b * 768 + i;
    float xr = (float)xgp[0], xz = (float)xgp[256], xn = (float)xgp[512];
    xgp += (size_t)64 * 768;

    int cur = 0;
    for (int t = 0; t < len; ++t) {
        // prefetch next step's xg (last iter reads 64 rows past -> still inside ws; unused)
        float pxr = (float)xgp[0], pxz = (float)xgp[256], pxn = (float)xgp[512];
        xgp += (size_t)64 * 768;

        float a0 = 0.f, a1 = 0.f, a2 = 0.f;
        int   i0 = 0,   i1 = 0,   i2 = 0;

        // fp16 half: h cols [0,128) broadcast from hbuf
        const uint4* hp = (const uint4*)&hbuf[cur][0];   // 16 uint4 = 64 h2
#pragma unroll
        for (int q = 0; q < 16; ++q) {
            uint4 hv = hp[q];
            h2_t h0 = BC2(hv.x), h1 = BC2(hv.y), h2v = BC2(hv.z), h3 = BC2(hv.w);
            a0 = __builtin_amdgcn_fdot2(w0[q * 4 + 0], h0, a0, false);
            a1 = __builtin_amdgcn_fdot2(w1[q * 4 + 0], h0, a1, false);
            a2 = __builtin_amdgcn_fdot2(w2[q * 4 + 0], h0, a2, false);
            a0 = __builtin_amdgcn_fdot2(w0[q * 4 + 1], h1, a0, false);
            a1 = __builtin_amdgcn_fdot2(w1[q * 4 + 1], h1, a1, false);
            a2 = __builtin_amdgcn_fdot2(w2[q * 4 + 1], h1, a2, false);
            a0 = __builtin_amdgcn_fdot2(w0[q * 4 + 2], h2v, a0, false);
            a1 = __builtin_amdgcn_fdot2(w1[q * 4 + 2], h2v, a1, false);
            a2 = __builtin_amdgcn_fdot2(w2[q * 4 + 2], h2v, a2, false);
            a0 = __builtin_amdgcn_fdot2(w0[q * 4 + 3], h3, a0, false);
            a1 = __builtin_amdgcn_fdot2(w1[q * 4 + 3], h3, a1, false);
            a2 = __builtin_amdgcn_fdot2(w2[q * 4 + 3], h3, a2, false);
        }
        // int8 half: h cols [128,256) quantized, weights from LDS
        const uint4* hqp = (const uint4*)&hq8[cur][0];   // 8 uint4 = 32 uints
#pragma unroll
        for (int k = 0; k < 8; ++k) {
            uint4 hv = hqp[k];
            uint4 wa = lw8q[0][k][i];
            uint4 wb = lw8q[1][k][i];
            uint4 wc = lw8q[2][k][i];
            i0 = SD4(wa.x, hv.x, i0); i0 = SD4(wa.y, hv.y, i0);
            i0 = SD4(wa.z, hv.z, i0); i0 = SD4(wa.w, hv.w, i0);
            i1 = SD4(wb.x, hv.x, i1); i1 = SD4(wb.y, hv.y, i1);
            i1 = SD4(wb.z, hv.z, i1); i1 = SD4(wb.w, hv.w, i1);
            i2 = SD4(wc.x, hv.x, i2); i2 = SD4(wc.y, hv.y, i2);
            i2 = SD4(wc.z, hv.z, i2); i2 = SD4(wc.w, hv.w, i2);
        }

        float hr = a0 + (float)i0 * INV8 + bhr;
        float hz = a1 + (float)i1 * INV8 + bhz;
        float hn = a2 + (float)i2 * INV8 + bhn;
        float rg = 1.f / (1.f + __expf(-(xr + hr)));
        float zg = 1.f / (1.f + __expf(-(xz + hz)));
        float xnr = xn + rg * hn;
        float nv = 1.f - 2.f / (__expf(2.f * xnr) + 1.f);   // tanh
        h = (1.f - zg) * nv + zg * h;

        int nxt = cur ^ 1;
        hbuf[nxt][i] = (_Float16)h;
        if (i >= 128)
            ((char*)&hq8[nxt][0])[i - 128] = (char)(int)rintf(h * 127.f);

        float pc0 = cw0 * h, pc1 = cw1 * h;
#pragma unroll
        for (int off = 32; off; off >>= 1) {
            pc0 += __shfl_xor(pc0, off, 64);
            pc1 += __shfl_xor(pc1, off, 64);
        }
        if ((i & 63) == 0) {
            atomicAdd(&psum[((size_t)(t0 + t) * 64 + b) * 2 + 0], pc0);
            atomicAdd(&psum[((size_t)(t0 + t) * 64 + b) * 2 + 1], pc1);
        }
        __syncthreads();
        cur = nxt;
        xr = pxr; xz = pxz; xn = pxn;
    }
    hstate[(size_t)blk * 256 + i] = h;
}

// ---------------- final: sliding mean over W steps + clf bias ----------------
__global__ void final_kernel(const float* __restrict__ psum, const float* __restrict__ clf_b,
                             const int* __restrict__ win, float* __restrict__ out) {
    int idx = blockIdx.x * 256 + threadIdx.x;
    if (idx >= TOUT * 128) return;
    int c = idx & 1;
    int rem = idx >> 1;
    int b = rem & 63;
    int tau = rem >> 6;
    int W = win[0] - 5 + 1;   // 96
    float s = 0.f;
    for (int j = 0; j < W; ++j)
        s += psum[((size_t)(tau + j) * 64 + b) * 2 + c];
    out[idx] = s / (float)W + clf_b[c];
}

extern "C" void kernel_launch(void* const* d_in, const int* in_sizes, int n_in,
                              void* d_out, int out_size, void* d_ws, size_t ws_size,
                              hipStream_t stream) {
    const float* x      = (const float*)d_in[0];
    const float* conv_w = (const float*)d_in[1];
    const float* conv_b = (const float*)d_in[2];
    const float* w_ih_f = (const float*)d_in[3];
    const float* w_hh_f = (const float*)d_in[4];
    const float* b_ih_f = (const float*)d_in[5];
    const float* b_hh_f = (const float*)d_in[6];
    const float* w_ih_r = (const float*)d_in[7];
    const float* w_hh_r = (const float*)d_in[8];
    const float* b_ih_r = (const float*)d_in[9];
    const float* b_hh_r = (const float*)d_in[10];
    const float* clf_w  = (const float*)d_in[11];
    const float* clf_b  = (const float*)d_in[12];
    const int*   win    = (const int*)d_in[13];
    float* out = (float*)d_out;

    char* ws = (char*)d_ws;
    _Float16* seqc = (_Float16*)(ws + OFF_SEQC);
    _Float16* xg   = (_Float16*)(ws + OFF_XG);
    float*    wT   = (float*)(ws + OFF_WT);
    _Float16* wcat = (_Float16*)(ws + OFF_WCAT);
    float*    psum = (float*)(ws + OFF_PSUM);
    float*    hst  = (float*)(ws + OFF_HST);
    unsigned* wq8  = (unsigned*)(ws + OFF_WQ8);

    int prep_elems = 400 * 256 + NN * 256 + TC * 64 * 2 + 2 * 3 * 32 * 256;
    prep_kernel<<<(prep_elems + 255) / 256, 256, 0, stream>>>(
        conv_w, w_ih_f, w_ih_r, w_hh_f, w_hh_r, wT, wcat, psum, wq8);

    for (int c = 0; c < NCHK; ++c) {
        int t0  = c * TCH;
        int len = (c == NCHK - 1) ? (TC - t0) : TCH;   // 250 / last 246
        conv_kernel<<<dim3(4, 64), 256, 0, stream>>>(x, wT, conv_b, seqc, t0, len);
        proj_kernel<<<dim3(len * 64 / 128, 12), 256, 0, stream>>>(seqc, wcat, b_ih_f, b_ih_r, xg);
        scan_kernel<<<128, 256, 0, stream>>>(xg, w_hh_f, w_hh_r, b_hh_f, b_hh_r,
                                             clf_w, (const uint4*)wq8, psum, hst, t0, len, c == 0);
    }
    final_kernel<<<(TOUT * 128 + 255) / 256, 256, 0, stream>>>(psum, clf_b, win, out);
}

// Round 11
// 2488.692 us; speedup vs baseline: 1.7634x; 1.7634x over previous
//
#include <hip/hip_runtime.h>
#include <hip/hip_bf16.h>

// KWSNet: conv1d+relu -> 2x GRU (fwd-scan, two weight sets) -> sliding mean -> linear(2)
// B=64, M=80, T=2000, C=H=256, K=5; Tc=1996, W=96, Tout=1901, out (1901,1,64,2) fp32.
//
// Chunked pipeline (8 x <=250 steps): conv -> proj (fp16 MFMA) -> persistent GRU
// scan -> clf (classifier dot, off the scan's critical path).
//
// Scan (R11): R10 removed the scratch spill yet dur stayed 433us -> the real
// bound is the LDS pipe + exposed latency at 1 wave/SIMD (~240 DS instr/CU/step).
// Full-int8 recurrent weights fit ALL 256 cols in 192 VGPRs (3 gates x 64
// uints); h broadcast as 256B int8 (16 ds_read_b128) + 1 ds_write_b8 = the
// only LDS traffic. Classifier moved to a separate parallel kernel over a
// streamed enc buffer. Step budget ~700-900 cyc vs R10's 4150.

#define TT    2000
#define TC    1996
#define NB    64
#define MCH   80
#define NH    256
#define NN    1536           // 2 * 3H
#define TOUT  1901
#define TCH   250            // chunk length (last chunk = 246)
#define NCHK  8
#define CROWS (TCH * NB)     // 16000 rows per chunk

typedef _Float16 h2_t __attribute__((ext_vector_type(2)));
typedef _Float16 h8_t __attribute__((ext_vector_type(8)));
typedef float    f4_t __attribute__((ext_vector_type(4)));

#define WQSCALE 254.0f
#define INV8    (1.0f / (254.0f * 127.0f))

// ---------------- workspace layout (bytes), total ~76.5 MB ----------------
#define OFF_SEQC ((size_t)0)            // fp16 [CROWS][256]      = 8,192,000
#define OFF_XG   ((size_t)8192000)      // fp16 [2][CROWS][768]   = 49,152,000
#define OFF_WT   ((size_t)57344000)     // fp32 [400][256]        = 409,600
#define OFF_WCAT ((size_t)57753600)     // fp16 [1536][256]       = 786,432
#define OFF_PSUM ((size_t)58540032)     // fp32 [TC][64][2]       = 1,021,952
#define OFF_HST  ((size_t)59561984)     // fp32 [128][256]        = 131,072
#define OFF_WQ   ((size_t)59693056)     // u32  [2][3][256][64]   = 393,216  (int8 W_hh, all cols)
#define OFF_ENC  ((size_t)60086272)     // fp16 [TCH*64][512]     = 16,384,000

// ---------------- prep: transpose conv_w, fp16 w_ih concat, int8-quantize W_hh ----------------
__global__ void prep_kernel(const float* __restrict__ conv_w,
                            const float* __restrict__ wihf,
                            const float* __restrict__ wihr,
                            const float* __restrict__ whhf,
                            const float* __restrict__ whhr,
                            float* __restrict__ wT,
                            _Float16* __restrict__ wcat,
                            unsigned* __restrict__ wq) {
    int idx = blockIdx.x * 256 + threadIdx.x;
    if (idx < 400 * 256) {
        int c = idx & 255, mk = idx >> 8;
        wT[idx] = conv_w[c * 400 + mk];
    }
    int i2 = idx - 400 * 256;
    if (i2 >= 0 && i2 < NN * 256) {
        int k = i2 & 255, n = i2 >> 8;
        float v = (n < 768) ? wihf[n * 256 + k] : wihr[(n - 768) * 256 + k];
        wcat[i2] = (_Float16)v;
    }
    int i4 = idx - (400 * 256 + NN * 256);
    if (i4 >= 0 && i4 < 2 * 3 * 256 * 64) {
        // element (d,g,r,j): uint packs cols 4j..4j+3 of row g*256+r of whh_d
        int r  = i4 & 255;
        int j  = (i4 >> 8) & 63;
        int dg = i4 >> 14;               // 0..5 = d*3+g
        const float* whh = (dg >= 3) ? whhr : whhf;
        int g = (dg >= 3) ? dg - 3 : dg;
        const float* wp = whh + (size_t)(g * 256 + r) * 256 + 4 * j;
        unsigned v = 0;
#pragma unroll
        for (int kk = 0; kk < 4; ++kk) {
            float q = rintf(wp[kk] * WQSCALE);
            q = fminf(fmaxf(q, -127.f), 127.f);
            v |= ((unsigned)((int)q & 0xFF)) << (8 * kk);
        }
        wq[((size_t)dg * 256 + r) * 64 + j] = v;
    }
}

// ---------------- conv1d(valid,K=5)+bias+relu -> seqc fp16 [t_local*64+b][c] ----------------
__global__ __launch_bounds__(256, 2)
void conv_kernel(const float* __restrict__ x, const float* __restrict__ wT,
                 const float* __restrict__ conv_b, _Float16* __restrict__ seqc,
                 int t_base, int t_len) {
    __shared__ float xs[MCH][68];
    int tile = blockIdx.x;           // 0..3
    int b    = blockIdx.y;           // 0..63
    int tid  = threadIdx.x;
    for (int idx = tid; idx < MCH * 68; idx += 256) {
        int m = idx / 68, i = idx - m * 68;
        int tt = t_base + tile * 64 + i;
        xs[m][i] = (tt < TT) ? x[(size_t)b * (MCH * TT) + m * TT + tt] : 0.f;
    }
    __syncthreads();
    int lane = tid & 63, tg = tid >> 6;   // wave tg: t-range [tg*16, tg*16+16)
    float acc[4][16];
#pragma unroll
    for (int cq = 0; cq < 4; ++cq)
#pragma unroll
        for (int t = 0; t < 16; ++t) acc[cq][t] = 0.f;

    for (int m = 0; m < MCH; ++m) {
        float xr_[20];
#pragma unroll
        for (int q = 0; q < 5; ++q) {
            float4 v = *(const float4*)&xs[m][tg * 16 + q * 4];
            xr_[q * 4 + 0] = v.x; xr_[q * 4 + 1] = v.y;
            xr_[q * 4 + 2] = v.z; xr_[q * 4 + 3] = v.w;
        }
#pragma unroll
        for (int cq = 0; cq < 4; ++cq) {
            int c = lane + cq * 64;
            const float* wp = wT + (size_t)(m * 5) * 256 + c;
            float w0_ = wp[0], w1_ = wp[256], w2_ = wp[512], w3_ = wp[768], w4_ = wp[1024];
#pragma unroll
            for (int t = 0; t < 16; ++t)
                acc[cq][t] += w0_ * xr_[t] + w1_ * xr_[t + 1] + w2_ * xr_[t + 2]
                            + w3_ * xr_[t + 3] + w4_ * xr_[t + 4];
        }
    }
#pragma unroll
    for (int cq = 0; cq < 4; ++cq) {
        int c = lane + cq * 64;
        float cb = conv_b[c];
        for (int t = 0; t < 16; ++t) {
            int tl = tile * 64 + tg * 16 + t;     // t within chunk
            if (tl < t_len) {
                float v = acc[cq][t] + cb;
                v = v > 0.f ? v : 0.f;
                seqc[((size_t)tl * 64 + b) * 256 + c] = (_Float16)v;
            }
        }
    }
}

// ---------------- proj: xg[d][row][j] = seqc @ w_ih^T + b_ih (fp16 MFMA 16x16x32) ----------------
__global__ __launch_bounds__(256, 2)
void proj_kernel(const _Float16* __restrict__ seqc, const _Float16* __restrict__ wcat,
                 const float* __restrict__ bihf, const float* __restrict__ bihr,
                 _Float16* __restrict__ xg) {
    __shared__ __align__(16) _Float16 As[128][72];
    __shared__ __align__(16) _Float16 Bs[128][72];
    int row0 = blockIdx.x * 128;     // up to 125 tiles
    int n0   = blockIdx.y * 128;     // 12 tiles
    int tid  = threadIdx.x;
    int lane = tid & 63, wv = tid >> 6;
    int wr = wv >> 1, wc = wv & 1;                 // 2x2 waves of 64x64
    int fm = lane & 15, fq = lane >> 4;            // fragment index, quad
    f4_t acc[4][4];
#pragma unroll
    for (int mt = 0; mt < 4; ++mt)
#pragma unroll
        for (int nt = 0; nt < 4; ++nt) acc[mt][nt] = (f4_t){0.f, 0.f, 0.f, 0.f};

    int r = tid >> 1, part = tid & 1;
    for (int kc = 0; kc < 4; ++kc) {
        const uint4* srcA = (const uint4*)&seqc[(size_t)(row0 + r) * 256 + kc * 64 + part * 32];
        const uint4* srcB = (const uint4*)&wcat[(size_t)(n0 + r) * 256 + kc * 64 + part * 32];
        uint4* dstA = (uint4*)&As[r][part * 32];
        uint4* dstB = (uint4*)&Bs[r][part * 32];
        dstA[0] = srcA[0]; dstA[1] = srcA[1]; dstA[2] = srcA[2]; dstA[3] = srcA[3];
        dstB[0] = srcB[0]; dstB[1] = srcB[1]; dstB[2] = srcB[2]; dstB[3] = srcB[3];
        __syncthreads();
#pragma unroll
        for (int ks = 0; ks < 64; ks += 32) {
            h8_t af[4], bf[4];
#pragma unroll
            for (int mt = 0; mt < 4; ++mt)
                af[mt] = *(const h8_t*)&As[wr * 64 + mt * 16 + fm][ks + fq * 8];
#pragma unroll
            for (int nt = 0; nt < 4; ++nt)
                bf[nt] = *(const h8_t*)&Bs[wc * 64 + nt * 16 + fm][ks + fq * 8];
#pragma unroll
            for (int mt = 0; mt < 4; ++mt)
#pragma unroll
                for (int nt = 0; nt < 4; ++nt)
                    acc[mt][nt] = __builtin_amdgcn_mfma_f32_16x16x32_f16(
                        af[mt], bf[nt], acc[mt][nt], 0, 0, 0);
        }
        __syncthreads();
    }
    // epilogue: C col = lane&15 (n-dim), row = (lane>>4)*4 + reg (m-dim)
#pragma unroll
    for (int nt = 0; nt < 4; ++nt) {
        int col = n0 + wc * 64 + nt * 16 + fm;
        int d = (col < 768) ? 0 : 1;
        int j = col - d * 768;
        float bias = d ? bihr[j] : bihf[j];
        size_t obase = (size_t)d * CROWS * 768 + j;
#pragma unroll
        for (int mt = 0; mt < 4; ++mt) {
            int row = row0 + wr * 64 + mt * 16 + fq * 4;
#pragma unroll
            for (int rr = 0; rr < 4; ++rr)
                xg[obase + (size_t)(row + rr) * 768] = (_Float16)(acc[mt][nt][rr] + bias);
        }
    }
}

// ---------------- persistent GRU scan chunk: 1 block (256 thr) per (direction, batch) ----------------
#define SD4(a, b, c) __builtin_amdgcn_sdot4((int)(a), (int)(b), (c), false)

__global__ __launch_bounds__(256)
void scan_kernel(const _Float16* __restrict__ xg, const uint4* __restrict__ wq,
                 const float* __restrict__ bhhf, const float* __restrict__ bhhr,
                 float* __restrict__ hstate, _Float16* __restrict__ encc,
                 int t0, int len, int first) {
    int blk = blockIdx.x;
    int d = blk >> 6, b = blk & 63;
    int i = threadIdx.x;
    const float* bhh = d ? bhhr : bhhf;

    __shared__ __align__(16) unsigned hq8[2][64];   // int8 h, double-buffered (512 B)

    // int8 weights, rows {i, i+256, i+512}, all 256 cols: 48 uint4 = 192 VGPRs
    uint4 wa[16], wb[16], wc[16];
    {
        const uint4* pa = wq + ((size_t)(d * 3 + 0) * 256 + i) * 16;
        const uint4* pb = wq + ((size_t)(d * 3 + 1) * 256 + i) * 16;
        const uint4* pc = wq + ((size_t)(d * 3 + 2) * 256 + i) * 16;
#pragma unroll
        for (int k = 0; k < 16; ++k) { wa[k] = pa[k]; wb[k] = pb[k]; wc[k] = pc[k]; }
    }
    float bhr = bhh[i], bhz = bhh[256 + i], bhn = bhh[512 + i];
    float h = first ? 0.f : hstate[(size_t)blk * 256 + i];

    ((char*)&hq8[0][0])[i] = (char)(int)rintf(h * 127.f);
    __syncthreads();

    const _Float16* xgp = xg + (size_t)d * CROWS * 768 + (size_t)b * 768 + i;
    float xr = (float)xgp[0], xz = (float)xgp[256], xn = (float)xgp[512];
    xgp += (size_t)64 * 768;
    _Float16* ep = encc + (size_t)b * 512 + d * 256 + i;

    int cur = 0;
    for (int t = 0; t < len; ++t) {
        // prefetch next step's xg (last iter reads past chunk -> inside ws, unused)
        float pxr = (float)xgp[0], pxz = (float)xgp[256], pxn = (float)xgp[512];
        xgp += (size_t)64 * 768;

        const uint4* hqp = (const uint4*)&hq8[cur][0];   // 16 b128 broadcasts
        int i0 = 0, i1 = 0, i2 = 0;
#pragma unroll
        for (int k = 0; k < 16; ++k) {
            uint4 hv = hqp[k];
            i0 = SD4(wa[k].x, hv.x, i0); i0 = SD4(wa[k].y, hv.y, i0);
            i0 = SD4(wa[k].z, hv.z, i0); i0 = SD4(wa[k].w, hv.w, i0);
            i1 = SD4(wb[k].x, hv.x, i1); i1 = SD4(wb[k].y, hv.y, i1);
            i1 = SD4(wb[k].z, hv.z, i1); i1 = SD4(wb[k].w, hv.w, i1);
            i2 = SD4(wc[k].x, hv.x, i2); i2 = SD4(wc[k].y, hv.y, i2);
            i2 = SD4(wc[k].z, hv.z, i2); i2 = SD4(wc[k].w, hv.w, i2);
        }

        float hr = (float)i0 * INV8 + bhr;
        float hz = (float)i1 * INV8 + bhz;
        float hn = (float)i2 * INV8 + bhn;
        float rg = 1.f / (1.f + __expf(-(xr + hr)));
        float zg = 1.f / (1.f + __expf(-(xz + hz)));
        float xnr = xn + rg * hn;
        float nv = 1.f - 2.f / (__expf(2.f * xnr) + 1.f);   // tanh
        h = (1.f - zg) * nv + zg * h;

        int nxt = cur ^ 1;
        ((char*)&hq8[nxt][0])[i] = (char)(int)rintf(h * 127.f);
        ep[(size_t)t * 64 * 512] = (_Float16)h;             // stream enc (no dependency)
        __syncthreads();
        cur = nxt;
        xr = pxr; xz = pxz; xn = pxn;
    }
    hstate[(size_t)blk * 256 + i] = h;
}

// ---------------- clf: psum[t,b,c] = clf_w[c,:] . enc[t,b,:] (one wave per row) ----------------
__global__ __launch_bounds__(256)
void clf_kernel(const _Float16* __restrict__ encc, const float* __restrict__ clf_w,
                float* __restrict__ psum, int t0, int len) {
    int w = (blockIdx.x * 256 + threadIdx.x) >> 6;   // global wave index = tl*64+b
    int lane = threadIdx.x & 63;
    if (w >= len * 64) return;
    const _Float16* row = encc + (size_t)w * 512 + lane * 8;
    uint4 v = *(const uint4*)row;
    float4 c0a = *(const float4*)(clf_w + lane * 8);
    float4 c0b = *(const float4*)(clf_w + lane * 8 + 4);
    float4 c1a = *(const float4*)(clf_w + 512 + lane * 8);
    float4 c1b = *(const float4*)(clf_w + 512 + lane * 8 + 4);
    h2_t e0 = __builtin_bit_cast(h2_t, v.x), e1 = __builtin_bit_cast(h2_t, v.y);
    h2_t e2 = __builtin_bit_cast(h2_t, v.z), e3 = __builtin_bit_cast(h2_t, v.w);
    float s0 = c0a.x * (float)e0[0] + c0a.y * (float)e0[1] + c0a.z * (float)e1[0] + c0a.w * (float)e1[1]
             + c0b.x * (float)e2[0] + c0b.y * (float)e2[1] + c0b.z * (float)e3[0] + c0b.w * (float)e3[1];
    float s1 = c1a.x * (float)e0[0] + c1a.y * (float)e0[1] + c1a.z * (float)e1[0] + c1a.w * (float)e1[1]
             + c1b.x * (float)e2[0] + c1b.y * (float)e2[1] + c1b.z * (float)e3[0] + c1b.w * (float)e3[1];
#pragma unroll
    for (int off = 32; off; off >>= 1) {
        s0 += __shfl_xor(s0, off, 64);
        s1 += __shfl_xor(s1, off, 64);
    }
    if (lane == 0) {
        int tl = w >> 6, b = w & 63;
        psum[((size_t)(t0 + tl) * 64 + b) * 2 + 0] = s0;
        psum[((size_t)(t0 + tl) * 64 + b) * 2 + 1] = s1;
    }
}

// ---------------- final: sliding mean over W steps + clf bias ----------------
__global__ void final_kernel(const float* __restrict__ psum, const float* __restrict__ clf_b,
                             const int* __restrict__ win, float* __restrict__ out) {
    int idx = blockIdx.x * 256 + threadIdx.x;
    if (idx >= TOUT * 128) return;
    int c = idx & 1;
    int rem = idx >> 1;
    int b = rem & 63;
    int tau = rem >> 6;
    int W = win[0] - 5 + 1;   // 96
    float s = 0.f;
    for (int j = 0; j < W; ++j)
        s += psum[((size_t)(tau + j) * 64 + b) * 2 + c];
    out[idx] = s / (float)W + clf_b[c];
}

extern "C" void kernel_launch(void* const* d_in, const int* in_sizes, int n_in,
                              void* d_out, int out_size, void* d_ws, size_t ws_size,
                              hipStream_t stream) {
    const float* x      = (const float*)d_in[0];
    const float* conv_w = (const float*)d_in[1];
    const float* conv_b = (const float*)d_in[2];
    const float* w_ih_f = (const float*)d_in[3];
    const float* w_hh_f = (const float*)d_in[4];
    const float* b_ih_f = (const float*)d_in[5];
    const float* b_hh_f = (const float*)d_in[6];
    const float* w_ih_r = (const float*)d_in[7];
    const float* w_hh_r = (const float*)d_in[8];
    const float* b_ih_r = (const float*)d_in[9];
    const float* b_hh_r = (const float*)d_in[10];
    const float* clf_w  = (const float*)d_in[11];
    const float* clf_b  = (const float*)d_in[12];
    const int*   win    = (const int*)d_in[13];
    float* out = (float*)d_out;

    char* ws = (char*)d_ws;
    _Float16* seqc = (_Float16*)(ws + OFF_SEQC);
    _Float16* xg   = (_Float16*)(ws + OFF_XG);
    float*    wT   = (float*)(ws + OFF_WT);
    _Float16* wcat = (_Float16*)(ws + OFF_WCAT);
    float*    psum = (float*)(ws + OFF_PSUM);
    float*    hst  = (float*)(ws + OFF_HST);
    unsigned* wq   = (unsigned*)(ws + OFF_WQ);
    _Float16* encc = (_Float16*)(ws + OFF_ENC);

    int prep_elems = 400 * 256 + NN * 256 + 2 * 3 * 256 * 64;
    prep_kernel<<<(prep_elems + 255) / 256, 256, 0, stream>>>(
        conv_w, w_ih_f, w_ih_r, w_hh_f, w_hh_r, wT, wcat, wq);

    for (int c = 0; c < NCHK; ++c) {
        int t0  = c * TCH;
        int len = (c == NCHK - 1) ? (TC - t0) : TCH;   // 250 / last 246
        conv_kernel<<<dim3(4, 64), 256, 0, stream>>>(x, wT, conv_b, seqc, t0, len);
        proj_kernel<<<dim3(len * 64 / 128, 12), 256, 0, stream>>>(seqc, wcat, b_ih_f, b_ih_r, xg);
        scan_kernel<<<128, 256, 0, stream>>>(xg, (const uint4*)wq, b_hh_f, b_hh_r,
                                             hst, encc, t0, len, c == 0);
        clf_kernel<<<len * 16, 256, 0, stream>>>(encc, clf_w, psum, t0, len);
    }
    final_kernel<<<(TOUT * 128 + 255) / 256, 256, 0, stream>>>(psum, clf_b, win, out);
}

// Round 12
// 2478.681 us; speedup vs baseline: 1.7705x; 1.0040x over previous
//
#include <hip/hip_runtime.h>
#include <hip/hip_bf16.h>

// KWSNet: conv1d+relu -> 2x GRU (fwd-scan, two weight sets) -> sliding mean -> linear(2)
// B=64, M=80, T=2000, C=H=256, K=5; Tc=1996, W=96, Tout=1901, out (1901,1,64,2) fp32.
//
// Chunked pipeline (8 x <=250 steps): conv -> proj (fp16 MFMA) -> persistent GRU
// scan (full-int8 recurrent weights in VGPRs) -> clf -> final.
//
// R12: R11 cut scan 433->185us (LDS-pipe theory right) but VGPR_Count=128 shows
// the compiler kept the 48-uint4 weight set as per-step L2 reloads instead of
// registers (no spill stores; FETCH hides it since wq is L2-resident). For
// B=256 the only observed config granting >128 regs is big-LDS (R10: 99840B
// LDS -> 200 regs). So: add a 96KB live pad (R9-proven anti-DCE pattern) to
// force 1 block/CU and unlock the ~210-reg grant -> weights truly resident.

#define TT    2000
#define TC    1996
#define NB    64
#define MCH   80
#define NH    256
#define NN    1536           // 2 * 3H
#define TOUT  1901
#define TCH   250            // chunk length (last chunk = 246)
#define NCHK  8
#define CROWS (TCH * NB)     // 16000 rows per chunk

typedef _Float16 h2_t __attribute__((ext_vector_type(2)));
typedef _Float16 h8_t __attribute__((ext_vector_type(8)));
typedef float    f4_t __attribute__((ext_vector_type(4)));

#define WQSCALE 254.0f
#define INV8    (1.0f / (254.0f * 127.0f))

// ---------------- workspace layout (bytes), total ~76.5 MB ----------------
#define OFF_SEQC ((size_t)0)            // fp16 [CROWS][256]      = 8,192,000
#define OFF_XG   ((size_t)8192000)      // fp16 [2][CROWS][768]   = 49,152,000
#define OFF_WT   ((size_t)57344000)     // fp32 [400][256]        = 409,600
#define OFF_WCAT ((size_t)57753600)     // fp16 [1536][256]       = 786,432
#define OFF_PSUM ((size_t)58540032)     // fp32 [TC][64][2]       = 1,021,952
#define OFF_HST  ((size_t)59561984)     // fp32 [128][256]        = 131,072
#define OFF_WQ   ((size_t)59693056)     // u32  [2][3][256][64]   = 393,216  (int8 W_hh, all cols)
#define OFF_ENC  ((size_t)60086272)     // fp16 [TCH*64][512]     = 16,384,000

// ---------------- prep: transpose conv_w, fp16 w_ih concat, int8-quantize W_hh ----------------
__global__ void prep_kernel(const float* __restrict__ conv_w,
                            const float* __restrict__ wihf,
                            const float* __restrict__ wihr,
                            const float* __restrict__ whhf,
                            const float* __restrict__ whhr,
                            float* __restrict__ wT,
                            _Float16* __restrict__ wcat,
                            unsigned* __restrict__ wq) {
    int idx = blockIdx.x * 256 + threadIdx.x;
    if (idx < 400 * 256) {
        int c = idx & 255, mk = idx >> 8;
        wT[idx] = conv_w[c * 400 + mk];
    }
    int i2 = idx - 400 * 256;
    if (i2 >= 0 && i2 < NN * 256) {
        int k = i2 & 255, n = i2 >> 8;
        float v = (n < 768) ? wihf[n * 256 + k] : wihr[(n - 768) * 256 + k];
        wcat[i2] = (_Float16)v;
    }
    int i4 = idx - (400 * 256 + NN * 256);
    if (i4 >= 0 && i4 < 2 * 3 * 256 * 64) {
        // element (d,g,r,j): uint packs cols 4j..4j+3 of row g*256+r of whh_d
        int r  = i4 & 255;
        int j  = (i4 >> 8) & 63;
        int dg = i4 >> 14;               // 0..5 = d*3+g
        const float* whh = (dg >= 3) ? whhr : whhf;
        int g = (dg >= 3) ? dg - 3 : dg;
        const float* wp = whh + (size_t)(g * 256 + r) * 256 + 4 * j;
        unsigned v = 0;
#pragma unroll
        for (int kk = 0; kk < 4; ++kk) {
            float q = rintf(wp[kk] * WQSCALE);
            q = fminf(fmaxf(q, -127.f), 127.f);
            v |= ((unsigned)((int)q & 0xFF)) << (8 * kk);
        }
        wq[((size_t)dg * 256 + r) * 64 + j] = v;
    }
}

// ---------------- conv1d(valid,K=5)+bias+relu -> seqc fp16 [t_local*64+b][c] ----------------
__global__ __launch_bounds__(256, 2)
void conv_kernel(const float* __restrict__ x, const float* __restrict__ wT,
                 const float* __restrict__ conv_b, _Float16* __restrict__ seqc,
                 int t_base, int t_len) {
    __shared__ float xs[MCH][68];
    int tile = blockIdx.x;           // 0..3
    int b    = blockIdx.y;           // 0..63
    int tid  = threadIdx.x;
    for (int idx = tid; idx < MCH * 68; idx += 256) {
        int m = idx / 68, i = idx - m * 68;
        int tt = t_base + tile * 64 + i;
        xs[m][i] = (tt < TT) ? x[(size_t)b * (MCH * TT) + m * TT + tt] : 0.f;
    }
    __syncthreads();
    int lane = tid & 63, tg = tid >> 6;   // wave tg: t-range [tg*16, tg*16+16)
    float acc[4][16];
#pragma unroll
    for (int cq = 0; cq < 4; ++cq)
#pragma unroll
        for (int t = 0; t < 16; ++t) acc[cq][t] = 0.f;

    for (int m = 0; m < MCH; ++m) {
        float xr_[20];
#pragma unroll
        for (int q = 0; q < 5; ++q) {
            float4 v = *(const float4*)&xs[m][tg * 16 + q * 4];
            xr_[q * 4 + 0] = v.x; xr_[q * 4 + 1] = v.y;
            xr_[q * 4 + 2] = v.z; xr_[q * 4 + 3] = v.w;
        }
#pragma unroll
        for (int cq = 0; cq < 4; ++cq) {
            int c = lane + cq * 64;
            const float* wp = wT + (size_t)(m * 5) * 256 + c;
            float w0_ = wp[0], w1_ = wp[256], w2_ = wp[512], w3_ = wp[768], w4_ = wp[1024];
#pragma unroll
            for (int t = 0; t < 16; ++t)
                acc[cq][t] += w0_ * xr_[t] + w1_ * xr_[t + 1] + w2_ * xr_[t + 2]
                            + w3_ * xr_[t + 3] + w4_ * xr_[t + 4];
        }
    }
#pragma unroll
    for (int cq = 0; cq < 4; ++cq) {
        int c = lane + cq * 64;
        float cb = conv_b[c];
        for (int t = 0; t < 16; ++t) {
            int tl = tile * 64 + tg * 16 + t;     // t within chunk
            if (tl < t_len) {
                float v = acc[cq][t] + cb;
                v = v > 0.f ? v : 0.f;
                seqc[((size_t)tl * 64 + b) * 256 + c] = (_Float16)v;
            }
        }
    }
}

// ---------------- proj: xg[d][row][j] = seqc @ w_ih^T + b_ih (fp16 MFMA 16x16x32) ----------------
__global__ __launch_bounds__(256, 2)
void proj_kernel(const _Float16* __restrict__ seqc, const _Float16* __restrict__ wcat,
                 const float* __restrict__ bihf, const float* __restrict__ bihr,
                 _Float16* __restrict__ xg) {
    __shared__ __align__(16) _Float16 As[128][72];
    __shared__ __align__(16) _Float16 Bs[128][72];
    int row0 = blockIdx.x * 128;     // up to 125 tiles
    int n0   = blockIdx.y * 128;     // 12 tiles
    int tid  = threadIdx.x;
    int lane = tid & 63, wv = tid >> 6;
    int wr = wv >> 1, wc = wv & 1;                 // 2x2 waves of 64x64
    int fm = lane & 15, fq = lane >> 4;            // fragment index, quad
    f4_t acc[4][4];
#pragma unroll
    for (int mt = 0; mt < 4; ++mt)
#pragma unroll
        for (int nt = 0; nt < 4; ++nt) acc[mt][nt] = (f4_t){0.f, 0.f, 0.f, 0.f};

    int r = tid >> 1, part = tid & 1;
    for (int kc = 0; kc < 4; ++kc) {
        const uint4* srcA = (const uint4*)&seqc[(size_t)(row0 + r) * 256 + kc * 64 + part * 32];
        const uint4* srcB = (const uint4*)&wcat[(size_t)(n0 + r) * 256 + kc * 64 + part * 32];
        uint4* dstA = (uint4*)&As[r][part * 32];
        uint4* dstB = (uint4*)&Bs[r][part * 32];
        dstA[0] = srcA[0]; dstA[1] = srcA[1]; dstA[2] = srcA[2]; dstA[3] = srcA[3];
        dstB[0] = srcB[0]; dstB[1] = srcB[1]; dstB[2] = srcB[2]; dstB[3] = srcB[3];
        __syncthreads();
#pragma unroll
        for (int ks = 0; ks < 64; ks += 32) {
            h8_t af[4], bf[4];
#pragma unroll
            for (int mt = 0; mt < 4; ++mt)
                af[mt] = *(const h8_t*)&As[wr * 64 + mt * 16 + fm][ks + fq * 8];
#pragma unroll
            for (int nt = 0; nt < 4; ++nt)
                bf[nt] = *(const h8_t*)&Bs[wc * 64 + nt * 16 + fm][ks + fq * 8];
#pragma unroll
            for (int mt = 0; mt < 4; ++mt)
#pragma unroll
                for (int nt = 0; nt < 4; ++nt)
                    acc[mt][nt] = __builtin_amdgcn_mfma_f32_16x16x32_f16(
                        af[mt], bf[nt], acc[mt][nt], 0, 0, 0);
        }
        __syncthreads();
    }
    // epilogue: C col = lane&15 (n-dim), row = (lane>>4)*4 + reg (m-dim)
#pragma unroll
    for (int nt = 0; nt < 4; ++nt) {
        int col = n0 + wc * 64 + nt * 16 + fm;
        int d = (col < 768) ? 0 : 1;
        int j = col - d * 768;
        float bias = d ? bihr[j] : bihf[j];
        size_t obase = (size_t)d * CROWS * 768 + j;
#pragma unroll
        for (int mt = 0; mt < 4; ++mt) {
            int row = row0 + wr * 64 + mt * 16 + fq * 4;
#pragma unroll
            for (int rr = 0; rr < 4; ++rr)
                xg[obase + (size_t)(row + rr) * 768] = (_Float16)(acc[mt][nt][rr] + bias);
        }
    }
}

// ---------------- persistent GRU scan chunk: 1 block (256 thr) per (direction, batch) ----------------
#define SD4(a, b, c) __builtin_amdgcn_sdot4((int)(a), (int)(b), (c), false)

__global__ __launch_bounds__(256)
void scan_kernel(const _Float16* __restrict__ xg, const uint4* __restrict__ wq,
                 const float* __restrict__ bhhf, const float* __restrict__ bhhr,
                 float* __restrict__ hstate, _Float16* __restrict__ encc,
                 int t0, int len, int first) {
    int blk = blockIdx.x;
    int d = blk >> 6, b = blk & 63;
    int i = threadIdx.x;
    const float* bhh = d ? bhhr : bhhf;

    __shared__ __align__(16) unsigned hq8[2][64];   // int8 h, double-buffered (512 B)
    __shared__ float lds_pad[24576];                // 96 KB: force 1 block/CU -> ~210-reg grant
    if (__builtin_expect(len < 0, 0)) {             // never true at runtime; anti-DCE dataflow
        lds_pad[i] = (float)first;
        lds_pad[256 + ((i * 37) & 16383)] = (float)i;
        __syncthreads();
        hstate[i] = lds_pad[255 - i] + lds_pad[256 + ((i * 131) & 16383)];
        return;
    }

    // int8 weights, rows {i, i+256, i+512}, all 256 cols: 48 uint4 = 192 VGPRs
    uint4 wa[16], wb[16], wc[16];
    {
        const uint4* pa = wq + ((size_t)(d * 3 + 0) * 256 + i) * 16;
        const uint4* pb = wq + ((size_t)(d * 3 + 1) * 256 + i) * 16;
        const uint4* pc = wq + ((size_t)(d * 3 + 2) * 256 + i) * 16;
#pragma unroll
        for (int k = 0; k < 16; ++k) { wa[k] = pa[k]; wb[k] = pb[k]; wc[k] = pc[k]; }
    }
    float bhr = bhh[i], bhz = bhh[256 + i], bhn = bhh[512 + i];
    float h = first ? 0.f : hstate[(size_t)blk * 256 + i];

    ((char*)&hq8[0][0])[i] = (char)(int)rintf(h * 127.f);
    __syncthreads();

    const _Float16* xgp = xg + (size_t)d * CROWS * 768 + (size_t)b * 768 + i;
    float xr = (float)xgp[0], xz = (float)xgp[256], xn = (float)xgp[512];
    xgp += (size_t)64 * 768;
    _Float16* ep = encc + (size_t)b * 512 + d * 256 + i;

    int cur = 0;
    for (int t = 0; t < len; ++t) {
        // prefetch next step's xg (last iter reads past chunk -> inside ws, unused)
        float pxr = (float)xgp[0], pxz = (float)xgp[256], pxn = (float)xgp[512];
        xgp += (size_t)64 * 768;

        const uint4* hqp = (const uint4*)&hq8[cur][0];   // 16 b128 broadcasts
        int i0 = 0, i1 = 0, i2 = 0;
#pragma unroll
        for (int k = 0; k < 16; ++k) {
            uint4 hv = hqp[k];
            i0 = SD4(wa[k].x, hv.x, i0); i0 = SD4(wa[k].y, hv.y, i0);
            i0 = SD4(wa[k].z, hv.z, i0); i0 = SD4(wa[k].w, hv.w, i0);
            i1 = SD4(wb[k].x, hv.x, i1); i1 = SD4(wb[k].y, hv.y, i1);
            i1 = SD4(wb[k].z, hv.z, i1); i1 = SD4(wb[k].w, hv.w, i1);
            i2 = SD4(wc[k].x, hv.x, i2); i2 = SD4(wc[k].y, hv.y, i2);
            i2 = SD4(wc[k].z, hv.z, i2); i2 = SD4(wc[k].w, hv.w, i2);
        }

        float hr = (float)i0 * INV8 + bhr;
        float hz = (float)i1 * INV8 + bhz;
        float hn = (float)i2 * INV8 + bhn;
        float rg = 1.f / (1.f + __expf(-(xr + hr)));
        float zg = 1.f / (1.f + __expf(-(xz + hz)));
        float xnr = xn + rg * hn;
        float nv = 1.f - 2.f / (__expf(2.f * xnr) + 1.f);   // tanh
        h = (1.f - zg) * nv + zg * h;

        int nxt = cur ^ 1;
        ((char*)&hq8[nxt][0])[i] = (char)(int)rintf(h * 127.f);
        ep[(size_t)t * 64 * 512] = (_Float16)h;             // stream enc (no dependency)
        __syncthreads();
        cur = nxt;
        xr = pxr; xz = pxz; xn = pxn;
    }
    hstate[(size_t)blk * 256 + i] = h;
}

// ---------------- clf: psum[t,b,c] = clf_w[c,:] . enc[t,b,:] (one wave per row) ----------------
__global__ __launch_bounds__(256)
void clf_kernel(const _Float16* __restrict__ encc, const float* __restrict__ clf_w,
                float* __restrict__ psum, int t0, int len) {
    int w = (blockIdx.x * 256 + threadIdx.x) >> 6;   // global wave index = tl*64+b
    int lane = threadIdx.x & 63;
    if (w >= len * 64) return;
    const _Float16* row = encc + (size_t)w * 512 + lane * 8;
    uint4 v = *(const uint4*)row;
    float4 c0a = *(const float4*)(clf_w + lane * 8);
    float4 c0b = *(const float4*)(clf_w + lane * 8 + 4);
    float4 c1a = *(const float4*)(clf_w + 512 + lane * 8);
    float4 c1b = *(const float4*)(clf_w + 512 + lane * 8 + 4);
    h2_t e0 = __builtin_bit_cast(h2_t, v.x), e1 = __builtin_bit_cast(h2_t, v.y);
    h2_t e2 = __builtin_bit_cast(h2_t, v.z), e3 = __builtin_bit_cast(h2_t, v.w);
    float s0 = c0a.x * (float)e0[0] + c0a.y * (float)e0[1] + c0a.z * (float)e1[0] + c0a.w * (float)e1[1]
             + c0b.x * (float)e2[0] + c0b.y * (float)e2[1] + c0b.z * (float)e3[0] + c0b.w * (float)e3[1];
    float s1 = c1a.x * (float)e0[0] + c1a.y * (float)e0[1] + c1a.z * (float)e1[0] + c1a.w * (float)e1[1]
             + c1b.x * (float)e2[0] + c1b.y * (float)e2[1] + c1b.z * (float)e3[0] + c1b.w * (float)e3[1];
#pragma unroll
    for (int off = 32; off; off >>= 1) {
        s0 += __shfl_xor(s0, off, 64);
        s1 += __shfl_xor(s1, off, 64);
    }
    if (lane == 0) {
        int tl = w >> 6, b = w & 63;
        psum[((size_t)(t0 + tl) * 64 + b) * 2 + 0] = s0;
        psum[((size_t)(t0 + tl) * 64 + b) * 2 + 1] = s1;
    }
}

// ---------------- final: sliding mean over W steps + clf bias ----------------
__global__ void final_kernel(const float* __restrict__ psum, const float* __restrict__ clf_b,
                             const int* __restrict__ win, float* __restrict__ out) {
    int idx = blockIdx.x * 256 + threadIdx.x;
    if (idx >= TOUT * 128) return;
    int c = idx & 1;
    int rem = idx >> 1;
    int b = rem & 63;
    int tau = rem >> 6;
    int W = win[0] - 5 + 1;   // 96
    float s = 0.f;
    for (int j = 0; j < W; ++j)
        s += psum[((size_t)(tau + j) * 64 + b) * 2 + c];
    out[idx] = s / (float)W + clf_b[c];
}

extern "C" void kernel_launch(void* const* d_in, const int* in_sizes, int n_in,
                              void* d_out, int out_size, void* d_ws, size_t ws_size,
                              hipStream_t stream) {
    const float* x      = (const float*)d_in[0];
    const float* conv_w = (const float*)d_in[1];
    const float* conv_b = (const float*)d_in[2];
    const float* w_ih_f = (const float*)d_in[3];
    const float* w_hh_f = (const float*)d_in[4];
    const float* b_ih_f = (const float*)d_in[5];
    const float* b_hh_f = (const float*)d_in[6];
    const float* w_ih_r = (const float*)d_in[7];
    const float* w_hh_r = (const float*)d_in[8];
    const float* b_ih_r = (const float*)d_in[9];
    const float* b_hh_r = (const float*)d_in[10];
    const float* clf_w  = (const float*)d_in[11];
    const float* clf_b  = (const float*)d_in[12];
    const int*   win    = (const int*)d_in[13];
    float* out = (float*)d_out;

    char* ws = (char*)d_ws;
    _Float16* seqc = (_Float16*)(ws + OFF_SEQC);
    _Float16* xg   = (_Float16*)(ws + OFF_XG);
    float*    wT   = (float*)(ws + OFF_WT);
    _Float16* wcat = (_Float16*)(ws + OFF_WCAT);
    float*    psum = (float*)(ws + OFF_PSUM);
    float*    hst  = (float*)(ws + OFF_HST);
    unsigned* wq   = (unsigned*)(ws + OFF_WQ);
    _Float16* encc = (_Float16*)(ws + OFF_ENC);

    int prep_elems = 400 * 256 + NN * 256 + 2 * 3 * 256 * 64;
    prep_kernel<<<(prep_elems + 255) / 256, 256, 0, stream>>>(
        conv_w, w_ih_f, w_ih_r, w_hh_f, w_hh_r, wT, wcat, wq);

    for (int c = 0; c < NCHK; ++c) {
        int t0  = c * TCH;
        int len = (c == NCHK - 1) ? (TC - t0) : TCH;   // 250 / last 246
        conv_kernel<<<dim3(4, 64), 256, 0, stream>>>(x, wT, conv_b, seqc, t0, len);
        proj_kernel<<<dim3(len * 64 / 128, 12), 256, 0, stream>>>(seqc, wcat, b_ih_f, b_ih_r, xg);
        scan_kernel<<<128, 256, 0, stream>>>(xg, (const uint4*)wq, b_hh_f, b_hh_r,
                                             hst, encc, t0, len, c == 0);
        clf_kernel<<<len * 16, 256, 0, stream>>>(encc, clf_w, psum, t0, len);
    }
    final_kernel<<<(TOUT * 128 + 255) / 256, 256, 0, stream>>>(psum, clf_b, win, out);
}